// Round 1
// baseline (398.993 us; speedup 1.0000x reference)
//
#include <hip/hip_runtime.h>
#include <hip/hip_bf16.h>

#define HIDDEN 1024
#define B_SZ 32
#define S_SZ 2048
#define M_TOT (B_SZ * S_SZ)          // 65536 rows
#define MASKED_BIAS -10000.0f

using bf16   = __bf16;
using bf16x4 = __attribute__((ext_vector_type(4))) __bf16;
using bf16x8 = __attribute__((ext_vector_type(8))) __bf16;
using f32x4  = __attribute__((ext_vector_type(4))) float;

__device__ __forceinline__ float tanh_fast(float x) {
    float xc = fminf(fmaxf(x, -15.f), 15.f);
    float e2 = __expf(2.f * xc);
    return (e2 - 1.f) * __frcp_rn(e2 + 1.f);
}

// ---------------------------------------------------------------------------
// Kernel 1: hl_plus[b][g] = dot(h[b,:], W_h[g,:]) + b_h[g] + b_K[g] + b_cov[g]
// one wave per (b,g) dot; waves in a block share g (L1 reuse of W_h row)
// ---------------------------------------------------------------------------
__global__ __launch_bounds__(256) void k_hlplus(
    const float* __restrict__ h, const float* __restrict__ W_h,
    const float* __restrict__ b_h, const float* __restrict__ b_K,
    const float* __restrict__ b_cov, float* __restrict__ hl_plus)
{
    int wid  = blockIdx.x * 4 + (threadIdx.x >> 6);  // 0..32767
    int lane = threadIdx.x & 63;
    int b = wid & 31;
    int g = wid >> 5;
    const float4* hv = (const float4*)(h + b * HIDDEN);
    const float4* wv = (const float4*)(W_h + g * HIDDEN);
    float acc = 0.f;
#pragma unroll
    for (int i = 0; i < 4; ++i) {
        float4 a = hv[i * 64 + lane];
        float4 w = wv[i * 64 + lane];
        acc += a.x * w.x + a.y * w.y + a.z * w.z + a.w * w.w;
    }
#pragma unroll
    for (int off = 32; off; off >>= 1) acc += __shfl_xor(acc, off);
    if (lane == 0)
        hl_plus[b * HIDDEN + g] = acc + b_h[g] + b_K[g] + b_cov[g];
}

// ---------------------------------------------------------------------------
// Kernel 2: fused  e_part[nt][row] = sum_{g in tile} tanh(K@W_K^T + hl_plus
//                                     + cov*W_cov) * W_v[g]
// 128x128 tile, BK=32, 4 waves, bf16 MFMA 16x16x32, double-buffered LDS,
// reg-staged f32->bf16 conversion.
// ---------------------------------------------------------------------------
#define BM 128
#define BN 128
#define BK 32

__global__ __launch_bounds__(256) void k_fused(
    const float* __restrict__ Kin,      // [65536][1024]
    const float* __restrict__ W_K,      // [1024][1024]
    const float* __restrict__ hl_plus,  // [32][1024]
    const float* __restrict__ W_cov,    // [1024]
    const float* __restrict__ cov,      // [65536] flat (b*2048+s)
    const float* __restrict__ W_v,      // [1024]
    float* __restrict__ e_part)         // [8][65536]
{
    __shared__ __align__(16) bf16 As[2][BM][BK];   // 8 KB each buf
    __shared__ __align__(16) bf16 Bs[2][BN][BK];
    __shared__ float e_buf[BM][2];

    const int tid  = threadIdx.x;
    const int mt   = blockIdx.x >> 3;   // 512 m-tiles
    const int nt   = blockIdx.x & 7;    // 8 n-tiles (fastest -> A-panel L2 reuse)
    const int row0 = mt * BM;
    const int col0 = nt * BN;

    const int w    = tid >> 6;
    const int lane = tid & 63;
    const int wr   = w >> 1, wc = w & 1;
    const int lr   = lane & 15, kb = lane >> 4;

    // staging: chunk c = i*256+tid -> row = i*32 + (tid>>3), float4-col = tid&7
    const int sr  = tid >> 3;
    const int sc4 = tid & 7;
    const float4* Ag = (const float4*)(Kin + (size_t)row0 * HIDDEN);
    const float4* Bg = (const float4*)(W_K + (size_t)col0 * HIDDEN);

    float4 ar[4], br[4];

    auto LOAD = [&](int kt) {
        int kc4 = kt * 8;
#pragma unroll
        for (int i = 0; i < 4; ++i) {
            ar[i] = Ag[(i * 32 + sr) * 256 + kc4 + sc4];
            br[i] = Bg[(i * 32 + sr) * 256 + kc4 + sc4];
        }
    };
    auto STORE = [&](int buf) {
#pragma unroll
        for (int i = 0; i < 4; ++i) {
            bf16x4 av = { (bf16)ar[i].x, (bf16)ar[i].y, (bf16)ar[i].z, (bf16)ar[i].w };
            bf16x4 bv = { (bf16)br[i].x, (bf16)br[i].y, (bf16)br[i].z, (bf16)br[i].w };
            *(bf16x4*)&As[buf][i * 32 + sr][sc4 * 4] = av;
            *(bf16x4*)&Bs[buf][i * 32 + sr][sc4 * 4] = bv;
        }
    };

    f32x4 acc[4][4] = {};

    LOAD(0);
    for (int kt = 0; kt < HIDDEN / BK; ++kt) {
        int buf = kt & 1;
        STORE(buf);
        if (kt < HIDDEN / BK - 1) LOAD(kt + 1);
        __syncthreads();
        bf16x8 afr[4], bfr[4];
#pragma unroll
        for (int m = 0; m < 4; ++m)
            afr[m] = *(const bf16x8*)&As[buf][wr * 64 + m * 16 + lr][kb * 8];
#pragma unroll
        for (int n = 0; n < 4; ++n)
            bfr[n] = *(const bf16x8*)&Bs[buf][wc * 64 + n * 16 + lr][kb * 8];
#pragma unroll
        for (int m = 0; m < 4; ++m)
#pragma unroll
            for (int n = 0; n < 4; ++n)
                acc[m][n] = __builtin_amdgcn_mfma_f32_16x16x32_bf16(
                    afr[m], bfr[n], acc[m][n], 0, 0, 0);
        // single barrier per iter: next iter writes the OTHER buffer; the
        // iter-(kt+1) barrier separates these reads from iter-(kt+2) writes.
    }

    // ------------------- epilogue: tanh + dot(W_v) reduction ----------------
    const int bidx = row0 >> 11;                  // batch: tiles never straddle
    float hlv[4], wcv[4], wvv[4];
#pragma unroll
    for (int n = 0; n < 4; ++n) {
        int g = col0 + wc * 64 + n * 16 + lr;
        hlv[n] = hl_plus[bidx * HIDDEN + g];
        wcv[n] = W_cov[g];
        wvv[n] = W_v[g];
    }
#pragma unroll
    for (int m = 0; m < 4; ++m) {
#pragma unroll
        for (int i = 0; i < 4; ++i) {
            int rloc = wr * 64 + m * 16 + kb * 4 + i;
            float cv = cov[row0 + rloc];
            float ep = 0.f;
#pragma unroll
            for (int n = 0; n < 4; ++n) {
                float arg = acc[m][n][i] + hlv[n] + cv * wcv[n];
                ep += tanh_fast(arg) * wvv[n];
            }
            ep += __shfl_xor(ep, 1);
            ep += __shfl_xor(ep, 2);
            ep += __shfl_xor(ep, 4);
            ep += __shfl_xor(ep, 8);
            if (lr == 0) e_buf[rloc][wc] = ep;
        }
    }
    __syncthreads();
    if (tid < BM)
        e_part[(size_t)nt * M_TOT + row0 + tid] = e_buf[tid][0] + e_buf[tid][1];
}

// ---------------------------------------------------------------------------
// Kernel 3: per-batch softmax over S=2048; also emits cov_new = cov + a
// ---------------------------------------------------------------------------
__global__ __launch_bounds__(256) void k_softmax(
    const float* __restrict__ e_part, const float* __restrict__ mask,
    const float* __restrict__ cov, const float* __restrict__ b_v,
    float* __restrict__ a_out, float* __restrict__ cov_out)
{
    __shared__ float red[8];
    int b = blockIdx.x, tid = threadIdx.x;
    float bv = b_v[0];
    float ev[8];
    float mx = -1e30f;
#pragma unroll
    for (int j = 0; j < 8; ++j) {
        int s = j * 256 + tid;
        int idx = b * S_SZ + s;
        float e = bv;
#pragma unroll
        for (int p = 0; p < 8; ++p) e += e_part[(size_t)p * M_TOT + idx];
        e += mask[idx] * MASKED_BIAS;
        ev[j] = e;
        mx = fmaxf(mx, e);
    }
#pragma unroll
    for (int off = 32; off; off >>= 1) mx = fmaxf(mx, __shfl_xor(mx, off));
    if ((tid & 63) == 0) red[tid >> 6] = mx;
    __syncthreads();
    mx = fmaxf(fmaxf(red[0], red[1]), fmaxf(red[2], red[3]));
    float sum = 0.f;
#pragma unroll
    for (int j = 0; j < 8; ++j) { ev[j] = __expf(ev[j] - mx); sum += ev[j]; }
#pragma unroll
    for (int off = 32; off; off >>= 1) sum += __shfl_xor(sum, off);
    if ((tid & 63) == 0) red[4 + (tid >> 6)] = sum;   // disjoint slots
    __syncthreads();
    sum = red[4] + red[5] + red[6] + red[7];
    float inv = 1.f / sum;
#pragma unroll
    for (int j = 0; j < 8; ++j) {
        int idx = b * S_SZ + j * 256 + tid;
        float a = ev[j] * inv;
        a_out[idx]   = a;
        cov_out[idx] = cov[idx] + a;
    }
}

// ---------------------------------------------------------------------------
// Kernel 4: context partials  part_out[b][sc][h] = sum_{s in chunk} a*K
// ---------------------------------------------------------------------------
__global__ __launch_bounds__(256) void k_ctx_part(
    const float* __restrict__ Kin, const float* __restrict__ a_out,
    float* __restrict__ part_out)
{
    int sc = blockIdx.x;   // 0..7
    int b  = blockIdx.y;   // 0..31
    int tid = threadIdx.x;
    const float4* Kb = (const float4*)(Kin + ((size_t)b * S_SZ + sc * 256) * HIDDEN);
    const float*  ab = a_out + b * S_SZ + sc * 256;
    float4 acc = {0.f, 0.f, 0.f, 0.f};
#pragma unroll 4
    for (int s = 0; s < 256; ++s) {
        float av = ab[s];
        float4 kv = Kb[(size_t)s * 256 + tid];
        acc.x += av * kv.x; acc.y += av * kv.y;
        acc.z += av * kv.z; acc.w += av * kv.w;
    }
    ((float4*)part_out)[((size_t)b * 8 + sc) * 256 + tid] = acc;
}

// ---------------------------------------------------------------------------
// Kernel 5: out[b][h] = sum_sc part_out[b][sc][h]
// ---------------------------------------------------------------------------
__global__ __launch_bounds__(256) void k_ctx_reduce(
    const float* __restrict__ part_out, float* __restrict__ out)
{
    int b = blockIdx.x, tid = threadIdx.x;
    float4 acc = {0.f, 0.f, 0.f, 0.f};
#pragma unroll
    for (int sc = 0; sc < 8; ++sc) {
        float4 v = ((const float4*)part_out)[((size_t)b * 8 + sc) * 256 + tid];
        acc.x += v.x; acc.y += v.y; acc.z += v.z; acc.w += v.w;
    }
    ((float4*)out)[b * 256 + tid] = acc;
}

// ---------------------------------------------------------------------------
extern "C" void kernel_launch(void* const* d_in, const int* in_sizes, int n_in,
                              void* d_out, int out_size, void* d_ws, size_t ws_size,
                              hipStream_t stream)
{
    const float* h     = (const float*)d_in[0];
    const float* Kin   = (const float*)d_in[1];
    const float* cov   = (const float*)d_in[2];
    const float* mask  = (const float*)d_in[3];
    const float* W_h   = (const float*)d_in[4];
    const float* b_h   = (const float*)d_in[5];
    const float* W_K   = (const float*)d_in[6];
    const float* b_K   = (const float*)d_in[7];
    const float* W_cov = (const float*)d_in[8];
    const float* b_cov = (const float*)d_in[9];
    const float* W_v   = (const float*)d_in[10];
    const float* b_v   = (const float*)d_in[11];

    float* out_ctx = (float*)d_out;            // 32*1024
    float* a_out   = out_ctx + B_SZ * HIDDEN;  // 32*2048
    float* cov_out = a_out + M_TOT;            // 32*2048

    float* ws       = (float*)d_ws;
    float* hl_plus  = ws;                       // 32768 f32
    float* e_part   = ws + 32768;               // 8*65536 f32
    float* part_out = e_part + 8 * M_TOT;       // 32*8*1024 f32
    // total ws use: ~3.3 MB

    k_hlplus<<<8192, 256, 0, stream>>>(h, W_h, b_h, b_K, b_cov, hl_plus);
    k_fused<<<(M_TOT / BM) * (HIDDEN / BN), 256, 0, stream>>>(
        Kin, W_K, hl_plus, W_cov, cov, W_v, e_part);
    k_softmax<<<B_SZ, 256, 0, stream>>>(e_part, mask, cov, b_v, a_out, cov_out);
    dim3 g4(8, B_SZ);
    k_ctx_part<<<g4, 256, 0, stream>>>(Kin, a_out, part_out);
    k_ctx_reduce<<<B_SZ, 256, 0, stream>>>(part_out, out_ctx);
}

// Round 2
// 345.339 us; speedup vs baseline: 1.1554x; 1.1554x over previous
//
#include <hip/hip_runtime.h>
#include <hip/hip_bf16.h>

#define HIDDEN 1024
#define B_SZ 32
#define S_SZ 2048
#define M_TOT (B_SZ * S_SZ)          // 65536 rows
#define MASKED_BIAS -10000.0f

using bf16   = __bf16;
using bf16x4 = __attribute__((ext_vector_type(4))) __bf16;
using bf16x8 = __attribute__((ext_vector_type(8))) __bf16;
using f32x4  = __attribute__((ext_vector_type(4))) float;

__device__ __forceinline__ float tanh_fast(float x) {
    float xc = fminf(fmaxf(x, -15.f), 15.f);
    float e2 = __expf(2.f * xc);
    return (e2 - 1.f) * __frcp_rn(e2 + 1.f);
}

// ---------------------------------------------------------------------------
// Kernel 1: hl_plus[b][g] = dot(h[b,:], W_h[g,:]) + b_h[g] + b_K[g] + b_cov[g]
// ---------------------------------------------------------------------------
__global__ __launch_bounds__(256) void k_hlplus(
    const float* __restrict__ h, const float* __restrict__ W_h,
    const float* __restrict__ b_h, const float* __restrict__ b_K,
    const float* __restrict__ b_cov, float* __restrict__ hl_plus)
{
    int wid  = blockIdx.x * 4 + (threadIdx.x >> 6);  // 0..32767
    int lane = threadIdx.x & 63;
    int b = wid & 31;
    int g = wid >> 5;
    const float4* hv = (const float4*)(h + b * HIDDEN);
    const float4* wv = (const float4*)(W_h + g * HIDDEN);
    float acc = 0.f;
#pragma unroll
    for (int i = 0; i < 4; ++i) {
        float4 a = hv[i * 64 + lane];
        float4 w = wv[i * 64 + lane];
        acc += a.x * w.x + a.y * w.y + a.z * w.z + a.w * w.w;
    }
#pragma unroll
    for (int off = 32; off; off >>= 1) acc += __shfl_xor(acc, off);
    if (lane == 0)
        hl_plus[b * HIDDEN + g] = acc + b_h[g] + b_K[g] + b_cov[g];
}

// ---------------------------------------------------------------------------
// Kernel 2: fused  e_part[nt][row] = sum_{g in tile} tanh(K@W_K^T + hl_plus
//                                     + cov*W_cov) * W_v[g]
// 128x128 tile, BK=32, 4 waves, bf16 MFMA 16x16x32, double-buffered LDS.
// R2: XCD-bijective block swizzle (A-panel reuse within one XCD L2) +
//     LDS row padding 32->40 bf16 (80B stride, conflict-free b128 phases).
// ---------------------------------------------------------------------------
#define BM 128
#define BN 128
#define BK 32
#define BKP 40   // padded LDS row: 80B, multiple of 16B, stride 20 banks

__global__ __launch_bounds__(256) void k_fused(
    const float* __restrict__ Kin,      // [65536][1024]
    const float* __restrict__ W_K,      // [1024][1024]
    const float* __restrict__ hl_plus,  // [32][1024]
    const float* __restrict__ W_cov,    // [1024]
    const float* __restrict__ cov,      // [65536] flat (b*2048+s)
    const float* __restrict__ W_v,      // [1024]
    float* __restrict__ e_part)         // [8][65536]
{
    __shared__ __align__(16) bf16 As[2][BM][BKP];   // 10 KB each buf
    __shared__ __align__(16) bf16 Bs[2][BN][BKP];
    __shared__ float e_buf[BM][2];

    const int tid = threadIdx.x;
    // XCD-bijective swizzle: hw blocks i with i%8==x go to XCD x; give XCD x
    // the contiguous logical range [x*512, (x+1)*512) so the 8 nt-blocks of
    // each m-tile share one L2. gridDim.x = 4096, 4096 % 8 == 0 -> bijective.
    const int bid = blockIdx.x;
    const int lid = (bid & 7) * (int)(gridDim.x >> 3) + (bid >> 3);
    const int mt  = lid >> 3;           // 512 m-tiles
    const int nt  = lid & 7;            // 8 n-tiles (fastest within XCD)
    const int row0 = mt * BM;
    const int col0 = nt * BN;

    const int w    = tid >> 6;
    const int lane = tid & 63;
    const int wr   = w >> 1, wc = w & 1;
    const int lr   = lane & 15, kb = lane >> 4;

    // staging: chunk c = i*256+tid -> row = i*32 + (tid>>3), float4-col = tid&7
    const int sr  = tid >> 3;
    const int sc4 = tid & 7;
    const float4* Ag = (const float4*)(Kin + (size_t)row0 * HIDDEN);
    const float4* Bg = (const float4*)(W_K + (size_t)col0 * HIDDEN);

    float4 ar[4], br[4];

    auto LOAD = [&](int kt) {
        int kc4 = kt * 8;
#pragma unroll
        for (int i = 0; i < 4; ++i) {
            ar[i] = Ag[(i * 32 + sr) * 256 + kc4 + sc4];
            br[i] = Bg[(i * 32 + sr) * 256 + kc4 + sc4];
        }
    };
    auto STORE = [&](int buf) {
#pragma unroll
        for (int i = 0; i < 4; ++i) {
            bf16x4 av = { (bf16)ar[i].x, (bf16)ar[i].y, (bf16)ar[i].z, (bf16)ar[i].w };
            bf16x4 bv = { (bf16)br[i].x, (bf16)br[i].y, (bf16)br[i].z, (bf16)br[i].w };
            *(bf16x4*)&As[buf][i * 32 + sr][sc4 * 4] = av;
            *(bf16x4*)&Bs[buf][i * 32 + sr][sc4 * 4] = bv;
        }
    };

    f32x4 acc[4][4] = {};

    LOAD(0);
    for (int kt = 0; kt < HIDDEN / BK; ++kt) {
        int buf = kt & 1;
        STORE(buf);
        if (kt < HIDDEN / BK - 1) LOAD(kt + 1);
        __syncthreads();
        bf16x8 afr[4], bfr[4];
#pragma unroll
        for (int m = 0; m < 4; ++m)
            afr[m] = *(const bf16x8*)&As[buf][wr * 64 + m * 16 + lr][kb * 8];
#pragma unroll
        for (int n = 0; n < 4; ++n)
            bfr[n] = *(const bf16x8*)&Bs[buf][wc * 64 + n * 16 + lr][kb * 8];
#pragma unroll
        for (int m = 0; m < 4; ++m)
#pragma unroll
            for (int n = 0; n < 4; ++n)
                acc[m][n] = __builtin_amdgcn_mfma_f32_16x16x32_bf16(
                    afr[m], bfr[n], acc[m][n], 0, 0, 0);
        // single barrier per iter: next iter writes the OTHER buffer; the
        // iter-(kt+1) barrier separates these reads from iter-(kt+2) writes.
    }

    // ------------------- epilogue: tanh + dot(W_v) reduction ----------------
    const int bidx = row0 >> 11;                  // batch: tiles never straddle
    float hlv[4], wcv[4], wvv[4];
#pragma unroll
    for (int n = 0; n < 4; ++n) {
        int g = col0 + wc * 64 + n * 16 + lr;
        hlv[n] = hl_plus[bidx * HIDDEN + g];
        wcv[n] = W_cov[g];
        wvv[n] = W_v[g];
    }
#pragma unroll
    for (int m = 0; m < 4; ++m) {
#pragma unroll
        for (int i = 0; i < 4; ++i) {
            int rloc = wr * 64 + m * 16 + kb * 4 + i;
            float cv = cov[row0 + rloc];
            float ep = 0.f;
#pragma unroll
            for (int n = 0; n < 4; ++n) {
                float arg = acc[m][n][i] + hlv[n] + cv * wcv[n];
                ep += tanh_fast(arg) * wvv[n];
            }
            ep += __shfl_xor(ep, 1);
            ep += __shfl_xor(ep, 2);
            ep += __shfl_xor(ep, 4);
            ep += __shfl_xor(ep, 8);
            if (lr == 0) e_buf[rloc][wc] = ep;
        }
    }
    __syncthreads();
    if (tid < BM)
        e_part[(size_t)nt * M_TOT + row0 + tid] = e_buf[tid][0] + e_buf[tid][1];
}

// ---------------------------------------------------------------------------
// Kernel 3: per-batch softmax over S=2048; also emits cov_new = cov + a
// ---------------------------------------------------------------------------
__global__ __launch_bounds__(256) void k_softmax(
    const float* __restrict__ e_part, const float* __restrict__ mask,
    const float* __restrict__ cov, const float* __restrict__ b_v,
    float* __restrict__ a_out, float* __restrict__ cov_out)
{
    __shared__ float red[8];
    int b = blockIdx.x, tid = threadIdx.x;
    float bv = b_v[0];
    float ev[8];
    float mx = -1e30f;
#pragma unroll
    for (int j = 0; j < 8; ++j) {
        int s = j * 256 + tid;
        int idx = b * S_SZ + s;
        float e = bv;
#pragma unroll
        for (int p = 0; p < 8; ++p) e += e_part[(size_t)p * M_TOT + idx];
        e += mask[idx] * MASKED_BIAS;
        ev[j] = e;
        mx = fmaxf(mx, e);
    }
#pragma unroll
    for (int off = 32; off; off >>= 1) mx = fmaxf(mx, __shfl_xor(mx, off));
    if ((tid & 63) == 0) red[tid >> 6] = mx;
    __syncthreads();
    mx = fmaxf(fmaxf(red[0], red[1]), fmaxf(red[2], red[3]));
    float sum = 0.f;
#pragma unroll
    for (int j = 0; j < 8; ++j) { ev[j] = __expf(ev[j] - mx); sum += ev[j]; }
#pragma unroll
    for (int off = 32; off; off >>= 1) sum += __shfl_xor(sum, off);
    if ((tid & 63) == 0) red[4 + (tid >> 6)] = sum;   // disjoint slots
    __syncthreads();
    sum = red[4] + red[5] + red[6] + red[7];
    float inv = 1.f / sum;
#pragma unroll
    for (int j = 0; j < 8; ++j) {
        int idx = b * S_SZ + j * 256 + tid;
        float a = ev[j] * inv;
        a_out[idx]   = a;
        cov_out[idx] = cov[idx] + a;
    }
}

// ---------------------------------------------------------------------------
// Kernel 4: context partials  part_out[b][sc][h] = sum_{s in chunk} a*K
// ---------------------------------------------------------------------------
__global__ __launch_bounds__(256) void k_ctx_part(
    const float* __restrict__ Kin, const float* __restrict__ a_out,
    float* __restrict__ part_out)
{
    int sc = blockIdx.x;   // 0..7
    int b  = blockIdx.y;   // 0..31
    int tid = threadIdx.x;
    const float4* Kb = (const float4*)(Kin + ((size_t)b * S_SZ + sc * 256) * HIDDEN);
    const float*  ab = a_out + b * S_SZ + sc * 256;
    float4 acc = {0.f, 0.f, 0.f, 0.f};
#pragma unroll 4
    for (int s = 0; s < 256; ++s) {
        float av = ab[s];
        float4 kv = Kb[(size_t)s * 256 + tid];
        acc.x += av * kv.x; acc.y += av * kv.y;
        acc.z += av * kv.z; acc.w += av * kv.w;
    }
    ((float4*)part_out)[((size_t)b * 8 + sc) * 256 + tid] = acc;
}

// ---------------------------------------------------------------------------
// Kernel 5: out[b][h] = sum_sc part_out[b][sc][h]
// ---------------------------------------------------------------------------
__global__ __launch_bounds__(256) void k_ctx_reduce(
    const float* __restrict__ part_out, float* __restrict__ out)
{
    int b = blockIdx.x, tid = threadIdx.x;
    float4 acc = {0.f, 0.f, 0.f, 0.f};
#pragma unroll
    for (int sc = 0; sc < 8; ++sc) {
        float4 v = ((const float4*)part_out)[((size_t)b * 8 + sc) * 256 + tid];
        acc.x += v.x; acc.y += v.y; acc.z += v.z; acc.w += v.w;
    }
    ((float4*)out)[b * 256 + tid] = acc;
}

// ---------------------------------------------------------------------------
extern "C" void kernel_launch(void* const* d_in, const int* in_sizes, int n_in,
                              void* d_out, int out_size, void* d_ws, size_t ws_size,
                              hipStream_t stream)
{
    const float* h     = (const float*)d_in[0];
    const float* Kin   = (const float*)d_in[1];
    const float* cov   = (const float*)d_in[2];
    const float* mask  = (const float*)d_in[3];
    const float* W_h   = (const float*)d_in[4];
    const float* b_h   = (const float*)d_in[5];
    const float* W_K   = (const float*)d_in[6];
    const float* b_K   = (const float*)d_in[7];
    const float* W_cov = (const float*)d_in[8];
    const float* b_cov = (const float*)d_in[9];
    const float* W_v   = (const float*)d_in[10];
    const float* b_v   = (const float*)d_in[11];

    float* out_ctx = (float*)d_out;            // 32*1024
    float* a_out   = out_ctx + B_SZ * HIDDEN;  // 32*2048
    float* cov_out = a_out + M_TOT;            // 32*2048

    float* ws       = (float*)d_ws;
    float* hl_plus  = ws;                       // 32768 f32
    float* e_part   = ws + 32768;               // 8*65536 f32
    float* part_out = e_part + 8 * M_TOT;       // 32*8*1024 f32
    // total ws use: ~3.3 MB

    k_hlplus<<<8192, 256, 0, stream>>>(h, W_h, b_h, b_K, b_cov, hl_plus);
    k_fused<<<(M_TOT / BM) * (HIDDEN / BN), 256, 0, stream>>>(
        Kin, W_K, hl_plus, W_cov, cov, W_v, e_part);
    k_softmax<<<B_SZ, 256, 0, stream>>>(e_part, mask, cov, b_v, a_out, cov_out);
    dim3 g4(8, B_SZ);
    k_ctx_part<<<g4, 256, 0, stream>>>(Kin, a_out, part_out);
    k_ctx_reduce<<<B_SZ, 256, 0, stream>>>(part_out, out_ctx);
}

// Round 3
// 331.390 us; speedup vs baseline: 1.2040x; 1.0421x over previous
//
#include <hip/hip_runtime.h>
#include <hip/hip_bf16.h>

#define HIDDEN 1024
#define B_SZ 32
#define S_SZ 2048
#define M_TOT (B_SZ * S_SZ)          // 65536 rows
#define MASKED_BIAS -10000.0f

using bf16   = __bf16;
using bf16x4 = __attribute__((ext_vector_type(4))) __bf16;
using bf16x8 = __attribute__((ext_vector_type(8))) __bf16;
using f32x4  = __attribute__((ext_vector_type(4))) float;

__device__ __forceinline__ float tanh_fast(float x) {
    float xc = fminf(fmaxf(x, -15.f), 15.f);
    float e2 = __expf(2.f * xc);
    return (e2 - 1.f) * __frcp_rn(e2 + 1.f);
}

// ---------------------------------------------------------------------------
// Kernel 1: hl_plus[b][g] = dot(h[b,:], W_h[g,:]) + b_h[g] + b_K[g] + b_cov[g]
// ---------------------------------------------------------------------------
__global__ __launch_bounds__(256) void k_hlplus(
    const float* __restrict__ h, const float* __restrict__ W_h,
    const float* __restrict__ b_h, const float* __restrict__ b_K,
    const float* __restrict__ b_cov, float* __restrict__ hl_plus)
{
    int wid  = blockIdx.x * 4 + (threadIdx.x >> 6);  // 0..32767
    int lane = threadIdx.x & 63;
    int b = wid & 31;
    int g = wid >> 5;
    const float4* hv = (const float4*)(h + b * HIDDEN);
    const float4* wv = (const float4*)(W_h + g * HIDDEN);
    float acc = 0.f;
#pragma unroll
    for (int i = 0; i < 4; ++i) {
        float4 a = hv[i * 64 + lane];
        float4 w = wv[i * 64 + lane];
        acc += a.x * w.x + a.y * w.y + a.z * w.z + a.w * w.w;
    }
#pragma unroll
    for (int off = 32; off; off >>= 1) acc += __shfl_xor(acc, off);
    if (lane == 0)
        hl_plus[b * HIDDEN + g] = acc + b_h[g] + b_K[g] + b_cov[g];
}

// ---------------------------------------------------------------------------
// Kernel 2: fused  e_part[nt][row] = sum_{g in tile} tanh(K@W_K^T + hl_plus
//                                     + cov*W_cov) * W_v[g]
// 128x128 tile, BK=32, 4 waves, bf16 MFMA 16x16x32.
// R3: raw s_barrier (lgkmcnt(0) only, NEVER vmcnt drain) + 2-deep register
//     prefetch pipeline + XOR-swizzled LDS (64B rows, col ^= (row&3)<<3).
// ---------------------------------------------------------------------------
#define BM 128
#define BN 128
#define BK 32

__global__ __launch_bounds__(256) void k_fused(
    const float* __restrict__ Kin,      // [65536][1024]
    const float* __restrict__ W_K,      // [1024][1024]
    const float* __restrict__ hl_plus,  // [32][1024]
    const float* __restrict__ W_cov,    // [1024]
    const float* __restrict__ cov,      // [65536] flat (b*2048+s)
    const float* __restrict__ W_v,      // [1024]
    float* __restrict__ e_part)         // [8][65536]
{
    __shared__ __align__(16) bf16 As[2][BM][BK];   // 8 KB each buf
    __shared__ __align__(16) bf16 Bs[2][BN][BK];
    __shared__ float e_buf[BM][2];

    const int tid = threadIdx.x;
    // XCD-bijective swizzle: 4096 % 8 == 0. The 8 nt-blocks of each m-tile
    // become same-XCD neighbors -> A-panel read once per XCD L2.
    const int bid = blockIdx.x;
    const int lid = (bid & 7) * (int)(gridDim.x >> 3) + (bid >> 3);
    const int mt  = lid >> 3;           // 512 m-tiles
    const int nt  = lid & 7;            // 8 n-tiles
    const int row0 = mt * BM;
    const int col0 = nt * BN;

    const int w    = tid >> 6;
    const int lane = tid & 63;
    const int wr   = w >> 1, wc = w & 1;
    const int lr   = lane & 15, kb = lane >> 4;

    // staging decomposition: thread -> row = i*32 + (tid>>3), float4-col = tid&7
    const int sr  = tid >> 3;
    const int sc4 = tid & 7;
    const float4* Ag = (const float4*)(Kin + (size_t)row0 * HIDDEN);
    const float4* Bg = (const float4*)(W_K + (size_t)col0 * HIDDEN);

    float4 ra[2][4], rb[2][4];

    // issue 8 global float4 loads for K-tile kt into register set SET
#define G_LOAD(SET, kt)                                                   \
    _Pragma("unroll") for (int i = 0; i < 4; ++i) {                       \
        ra[SET][i] = Ag[(i * 32 + sr) * 256 + (kt) * 8 + sc4];            \
        rb[SET][i] = Bg[(i * 32 + sr) * 256 + (kt) * 8 + sc4];            \
    }

    // cvt f32->bf16 and write set SET into LDS buffer BUF (XOR swizzle)
#define L_STORE(BUF, SET)                                                 \
    _Pragma("unroll") for (int i = 0; i < 4; ++i) {                       \
        int rw = i * 32 + sr;                                             \
        int cc = (sc4 * 4) ^ ((rw & 3) << 3);                             \
        bf16x4 av = { (bf16)ra[SET][i].x, (bf16)ra[SET][i].y,             \
                      (bf16)ra[SET][i].z, (bf16)ra[SET][i].w };           \
        bf16x4 bv = { (bf16)rb[SET][i].x, (bf16)rb[SET][i].y,             \
                      (bf16)rb[SET][i].z, (bf16)rb[SET][i].w };           \
        *(bf16x4*)&As[BUF][rw][cc] = av;                                  \
        *(bf16x4*)&Bs[BUF][rw][cc] = bv;                                  \
    }

    // raw barrier: drain LDS ops only; global loads stay in flight (counted
    // vmcnt emitted by the compiler at the consuming L_STORE).
#define BARRIER()                                                         \
    do {                                                                  \
        asm volatile("s_waitcnt lgkmcnt(0)" ::: "memory");                \
        __builtin_amdgcn_s_barrier();                                     \
        asm volatile("" ::: "memory");                                    \
    } while (0)

    f32x4 acc[4][4] = {};

#define MFMA_STEP(BUF)                                                    \
    {                                                                     \
        bf16x8 afr[4], bfr[4];                                            \
        _Pragma("unroll") for (int m = 0; m < 4; ++m) {                   \
            int rw = wr * 64 + m * 16 + lr;                               \
            afr[m] = *(const bf16x8*)&As[BUF][rw][(kb * 8) ^ ((rw & 3) << 3)]; \
        }                                                                 \
        _Pragma("unroll") for (int n = 0; n < 4; ++n) {                   \
            int rw = wc * 64 + n * 16 + lr;                               \
            bfr[n] = *(const bf16x8*)&Bs[BUF][rw][(kb * 8) ^ ((rw & 3) << 3)]; \
        }                                                                 \
        _Pragma("unroll") for (int m = 0; m < 4; ++m)                     \
            _Pragma("unroll") for (int n = 0; n < 4; ++n)                 \
                acc[m][n] = __builtin_amdgcn_mfma_f32_16x16x32_bf16(      \
                    afr[m], bfr[n], acc[m][n], 0, 0, 0);                  \
    }

    // ---- prologue: fill pipeline (sets 2-deep) ----
    G_LOAD(0, 0)
    G_LOAD(1, 1)
    L_STORE(0, 0)            // waits on set0 only (set1 stays in flight)
    G_LOAD(0, 2)
    BARRIER();

    // ---- main loop: kt = 0..27, invariant at even kt:
    //      set1 holds tile kt+1, set0 holds tile kt+2 (in flight) ----
    for (int kt2 = 0; kt2 < 14; ++kt2) {
        int kt = kt2 * 2;
        // even step (cur buf 0)
        L_STORE(1, 1)        // stage tile kt+1 into buf1
        G_LOAD(1, kt + 3)
        MFMA_STEP(0)
        BARRIER();
        // odd step (cur buf 1)
        L_STORE(0, 0)        // stage tile kt+2 into buf0
        G_LOAD(0, kt + 4)
        MFMA_STEP(1)
        BARRIER();
    }
    // ---- tail: kt = 28..31 ----
    L_STORE(1, 1)            // tile 29 -> buf1
    G_LOAD(1, 31)
    MFMA_STEP(0)
    BARRIER();
    L_STORE(0, 0)            // tile 30 -> buf0
    MFMA_STEP(1)
    BARRIER();
    L_STORE(1, 1)            // tile 31 -> buf1
    MFMA_STEP(0)
    BARRIER();
    MFMA_STEP(1)

    // ------------------- epilogue: tanh + dot(W_v) reduction ----------------
    const int bidx = row0 >> 11;                  // batch: tiles never straddle
    float hlv[4], wcv[4], wvv[4];
#pragma unroll
    for (int n = 0; n < 4; ++n) {
        int g = col0 + wc * 64 + n * 16 + lr;
        hlv[n] = hl_plus[bidx * HIDDEN + g];
        wcv[n] = W_cov[g];
        wvv[n] = W_v[g];
    }
#pragma unroll
    for (int m = 0; m < 4; ++m) {
#pragma unroll
        for (int i = 0; i < 4; ++i) {
            int rloc = wr * 64 + m * 16 + kb * 4 + i;
            float cv = cov[row0 + rloc];
            float ep = 0.f;
#pragma unroll
            for (int n = 0; n < 4; ++n) {
                float arg = acc[m][n][i] + hlv[n] + cv * wcv[n];
                ep += tanh_fast(arg) * wvv[n];
            }
            ep += __shfl_xor(ep, 1);
            ep += __shfl_xor(ep, 2);
            ep += __shfl_xor(ep, 4);
            ep += __shfl_xor(ep, 8);
            if (lr == 0) e_buf[rloc][wc] = ep;
        }
    }
    __syncthreads();
    if (tid < BM)
        e_part[(size_t)nt * M_TOT + row0 + tid] = e_buf[tid][0] + e_buf[tid][1];
}

// ---------------------------------------------------------------------------
// Kernel 3: per-batch softmax over S=2048; also emits cov_new = cov + a
// ---------------------------------------------------------------------------
__global__ __launch_bounds__(256) void k_softmax(
    const float* __restrict__ e_part, const float* __restrict__ mask,
    const float* __restrict__ cov, const float* __restrict__ b_v,
    float* __restrict__ a_out, float* __restrict__ cov_out)
{
    __shared__ float red[8];
    int b = blockIdx.x, tid = threadIdx.x;
    float bv = b_v[0];
    float ev[8];
    float mx = -1e30f;
#pragma unroll
    for (int j = 0; j < 8; ++j) {
        int s = j * 256 + tid;
        int idx = b * S_SZ + s;
        float e = bv;
#pragma unroll
        for (int p = 0; p < 8; ++p) e += e_part[(size_t)p * M_TOT + idx];
        e += mask[idx] * MASKED_BIAS;
        ev[j] = e;
        mx = fmaxf(mx, e);
    }
#pragma unroll
    for (int off = 32; off; off >>= 1) mx = fmaxf(mx, __shfl_xor(mx, off));
    if ((tid & 63) == 0) red[tid >> 6] = mx;
    __syncthreads();
    mx = fmaxf(fmaxf(red[0], red[1]), fmaxf(red[2], red[3]));
    float sum = 0.f;
#pragma unroll
    for (int j = 0; j < 8; ++j) { ev[j] = __expf(ev[j] - mx); sum += ev[j]; }
#pragma unroll
    for (int off = 32; off; off >>= 1) sum += __shfl_xor(sum, off);
    if ((tid & 63) == 0) red[4 + (tid >> 6)] = sum;   // disjoint slots
    __syncthreads();
    sum = red[4] + red[5] + red[6] + red[7];
    float inv = 1.f / sum;
#pragma unroll
    for (int j = 0; j < 8; ++j) {
        int idx = b * S_SZ + j * 256 + tid;
        float a = ev[j] * inv;
        a_out[idx]   = a;
        cov_out[idx] = cov[idx] + a;
    }
}

// ---------------------------------------------------------------------------
// Kernel 4: context partials  part_out[b][sc][h] = sum_{s in chunk} a*K
// ---------------------------------------------------------------------------
__global__ __launch_bounds__(256) void k_ctx_part(
    const float* __restrict__ Kin, const float* __restrict__ a_out,
    float* __restrict__ part_out)
{
    int sc = blockIdx.x;   // 0..7
    int b  = blockIdx.y;   // 0..31
    int tid = threadIdx.x;
    const float4* Kb = (const float4*)(Kin + ((size_t)b * S_SZ + sc * 256) * HIDDEN);
    const float*  ab = a_out + b * S_SZ + sc * 256;
    float4 acc = {0.f, 0.f, 0.f, 0.f};
#pragma unroll 4
    for (int s = 0; s < 256; ++s) {
        float av = ab[s];
        float4 kv = Kb[(size_t)s * 256 + tid];
        acc.x += av * kv.x; acc.y += av * kv.y;
        acc.z += av * kv.z; acc.w += av * kv.w;
    }
    ((float4*)part_out)[((size_t)b * 8 + sc) * 256 + tid] = acc;
}

// ---------------------------------------------------------------------------
// Kernel 5: out[b][h] = sum_sc part_out[b][sc][h]
// ---------------------------------------------------------------------------
__global__ __launch_bounds__(256) void k_ctx_reduce(
    const float* __restrict__ part_out, float* __restrict__ out)
{
    int b = blockIdx.x, tid = threadIdx.x;
    float4 acc = {0.f, 0.f, 0.f, 0.f};
#pragma unroll
    for (int sc = 0; sc < 8; ++sc) {
        float4 v = ((const float4*)part_out)[((size_t)b * 8 + sc) * 256 + tid];
        acc.x += v.x; acc.y += v.y; acc.z += v.z; acc.w += v.w;
    }
    ((float4*)out)[b * 256 + tid] = acc;
}

// ---------------------------------------------------------------------------
extern "C" void kernel_launch(void* const* d_in, const int* in_sizes, int n_in,
                              void* d_out, int out_size, void* d_ws, size_t ws_size,
                              hipStream_t stream)
{
    const float* h     = (const float*)d_in[0];
    const float* Kin   = (const float*)d_in[1];
    const float* cov   = (const float*)d_in[2];
    const float* mask  = (const float*)d_in[3];
    const float* W_h   = (const float*)d_in[4];
    const float* b_h   = (const float*)d_in[5];
    const float* W_K   = (const float*)d_in[6];
    const float* b_K   = (const float*)d_in[7];
    const float* W_cov = (const float*)d_in[8];
    const float* b_cov = (const float*)d_in[9];
    const float* W_v   = (const float*)d_in[10];
    const float* b_v   = (const float*)d_in[11];

    float* out_ctx = (float*)d_out;            // 32*1024
    float* a_out   = out_ctx + B_SZ * HIDDEN;  // 32*2048
    float* cov_out = a_out + M_TOT;            // 32*2048

    float* ws       = (float*)d_ws;
    float* hl_plus  = ws;                       // 32768 f32
    float* e_part   = ws + 32768;               // 8*65536 f32
    float* part_out = e_part + 8 * M_TOT;       // 32*8*1024 f32
    // total ws use: ~3.3 MB

    k_hlplus<<<8192, 256, 0, stream>>>(h, W_h, b_h, b_K, b_cov, hl_plus);
    k_fused<<<(M_TOT / BM) * (HIDDEN / BN), 256, 0, stream>>>(
        Kin, W_K, hl_plus, W_cov, cov, W_v, e_part);
    k_softmax<<<B_SZ, 256, 0, stream>>>(e_part, mask, cov, b_v, a_out, cov_out);
    dim3 g4(8, B_SZ);
    k_ctx_part<<<g4, 256, 0, stream>>>(Kin, a_out, part_out);
    k_ctx_reduce<<<B_SZ, 256, 0, stream>>>(part_out, out_ctx);
}